// Round 11
// baseline (15093.951 us; speedup 1.0000x reference)
//
#include <hip/hip_runtime.h>

typedef __bf16 bf16x8 __attribute__((ext_vector_type(8)));
typedef float f32x4 __attribute__((ext_vector_type(4)));
typedef unsigned short u16;
typedef unsigned u32;
typedef unsigned long long u64;

#define NSTEP 512

#define AL(p)   __hip_atomic_load((p), __ATOMIC_RELAXED, __HIP_MEMORY_SCOPE_AGENT)
#define AS(p,v) __hip_atomic_store((p), (v), __ATOMIC_RELAXED, __HIP_MEMORY_SCOPE_AGENT)

__device__ __forceinline__ u16 f2bf(float f) {
  union { float f; unsigned u; } x; x.f = f;
  return (u16)((x.u + 0x7fffu + ((x.u >> 16) & 1u)) >> 16);
}

// zero the tagged-h exchange buffers (tag 0 + h=0 is exactly step-0 input);
// runs every call -> deterministic replays
__global__ void prep_kernel(u64* __restrict__ X3) {
  int i = blockIdx.x * blockDim.x + threadIdx.x;
  int stride = gridDim.x * blockDim.x;
  for (int k = i; k < 3 * 64 * 512; k += stride) X3[k] = 0;
}

// A1[t*64+b][512] bf16 embedding gather
__global__ void gather_kernel(const int* __restrict__ sent, const float* __restrict__ emb,
                              u16* __restrict__ A1) {
  int row = blockIdx.x * 4 + (threadIdx.x >> 6);   // t*64+b
  int lane = threadIdx.x & 63;
  int t = row >> 6, b = row & 63;
  int idx = sent[b * 512 + t];
  const float* src = emb + (size_t)idx * 512 + lane * 8;
  u16* dst = A1 + (size_t)row * 512 + lane * 8;
  #pragma unroll
  for (int k = 0; k < 8; ++k) dst[k] = f2bf(src[k]);
}

// Exchange format: u64 = [epoch:32 | h(col+1):bf16 | h(col):bf16].
// X3[buf][row][slot], slot = col/2, 512 slots/row, buf = epoch%3.
struct G8 { u64 q[8][4]; };   // 8 fragments x 4 u64 (8 cols each) per thread

__device__ __forceinline__ bool stale(const G8& G, u32 T) {
  u32 bad = 0;
  #pragma unroll
  for (int f = 0; f < 8; ++f)
    #pragma unroll
    for (int e = 0; e < 4; ++e)
      bad |= ((u32)(G.q[f][e] >> 32)) ^ T;
  return bad != 0;
}
__device__ __forceinline__ bf16x8 fr(const G8& G, int f) {
  union { u32 d[4]; bf16x8 v; } u;
  #pragma unroll
  for (int e = 0; e < 4; ++e) u.d[e] = (u32)G.q[f][e];
  return u.v;
}

// 256 WGs x 256 thr. WG j owns h cols [j*4,j*4+4), 4 gates packed (rb = g*4+nn = lr).
// Weights in padded LDS. NO barrier, NO flags: pure dataflow via tagged h.
__global__ void __launch_bounds__(256, 1)
lstm_kernel(const u16* __restrict__ A1,
            const float* __restrict__ wih, const float* __restrict__ whh,
            const float* __restrict__ bih, const float* __restrict__ bhh,
            u64* __restrict__ X3, float* __restrict__ out) {
  __shared__ u16 wlds[48 * 16 * 36];        // 55296 B, stride-36 pad

  const int j   = blockIdx.x;
  const int tid = threadIdx.x;
  const int w   = tid >> 6;            // wave = batch tile 0..3
  const int l   = tid & 63;
  const int lr  = l & 15, lk = l >> 4;
  const int g   = lr >> 2, nn = lr & 3;
  const int wrow = g * 1024 + j * 4 + nn;

  // ---- stage ALL weights fp32->bf16 into padded LDS (once) ----
  for (int task = tid; task < 3072; task += 256) {
    int kk = task >> 6;                 // K chunk of 32 (0..47)
    int rem = task & 63;
    int rb = rem >> 2, q = rem & 3;
    int row = (rb >> 2) * 1024 + j * 4 + (rb & 3);
    const float* src = (kk < 16) ? (wih + (size_t)row * 512 + kk * 32 + q * 8)
                                 : (whh + (size_t)row * 1024 + (kk - 16) * 32 + q * 8);
    u16* dst = wlds + (kk * 16 + rb) * 36 + q * 8;
    #pragma unroll
    for (int e = 0; e < 8; ++e) dst[e] = f2bf(src[e]);
  }
  __syncthreads();

  const float bias = bih[wrow] + bhh[wrow];
  const float sca = (g == 2) ? 2.f : 1.f;   // tanh-as-sigmoid scaling
  const float bd  = (g == 2) ? -1.f : 0.f;
  const int arow = w * 16 + lr;             // batch row for A fragments
  const u16* bx = wlds + lr * 36 + lk * 8;  // + kk*576 per K chunk

  float cst[4] = {0.f, 0.f, 0.f, 0.f};

#define LDG(G, KK0)                                                         \
  { _Pragma("unroll")                                                       \
    for (int f = 0; f < 8; ++f) {                                           \
      const u64* p = Xc + ((KK0) + f) * 16 + lk * 4;                        \
      G.q[f][0] = AL(p);     G.q[f][1] = AL(p + 1);                         \
      G.q[f][2] = AL(p + 2); G.q[f][3] = AL(p + 3);                         \
    } }
#define MMG(G, KK0)                                                         \
  { _Pragma("unroll")                                                       \
    for (int f = 0; f < 8; ++f) {                                           \
      bf16x8 b = *(const bf16x8*)(bx + (16 + (KK0) + f) * 576);             \
      acc = __builtin_amdgcn_mfma_f32_16x16x32_bf16(fr(G, f), b, acc, 0, 0, 0); \
    } }

  #pragma unroll 1
  for (int t = 0; t < NSTEP; ++t) {
    const u32 tu = (u32)t;
    const u64* Xc = X3 + (size_t)(t % 3) * 32768 + (size_t)arow * 512;
    G8 ga, gb;
    LDG(ga, 0);                          // h group 0 in flight first
    // x-projection: A1 loads overlap the h-group latency
    bf16x8 ax[16];
    const u16* ap = A1 + ((size_t)t * 64 + arow) * 512 + lk * 8;
    #pragma unroll
    for (int kk = 0; kk < 16; ++kk) ax[kk] = *(const bf16x8*)(ap + kk * 32);
    f32x4 acc = { bias, bias, bias, bias };
    #pragma unroll
    for (int kk = 0; kk < 16; ++kk) {
      bf16x8 b = *(const bf16x8*)(bx + kk * 576);
      acc = __builtin_amdgcn_mfma_f32_16x16x32_bf16(ax[kk], b, acc, 0, 0, 0);
    }
    // h-projection: poll-retry groups pipelined against MFMA
    while (stale(ga, tu)) { LDG(ga, 0); }
    LDG(gb, 8);
    MMG(ga, 0);
    while (stale(gb, tu)) { LDG(gb, 8); }
    LDG(ga, 16);
    MMG(gb, 8);
    while (stale(ga, tu)) { LDG(ga, 16); }
    LDG(gb, 24);
    MMG(ga, 16);
    while (stale(gb, tu)) { LDG(gb, 24); }
    MMG(gb, 24);

    // activations + state update; lanes lr<4 own (rows lk*4+r, col j*4+lr)
    float hv4[4], cn4[4];
    #pragma unroll
    for (int r = 0; r < 4; ++r) {
      float xv = acc[r];
      float act = sca / (1.f + __expf(-sca * xv)) + bd;  // sigmoid / tanh
      float gg = __shfl_xor(act, 8);
      float ff = __shfl_xor(act, 4);
      float oo = __shfl_xor(act, 12);
      float cn = ff * cst[r] + act * gg;   // act = i at lanes lr<4
      cst[r] = cn;
      float tc = 2.f / (1.f + __expf(-2.f * cn)) - 1.f;
      hv4[r] = oo * tc;
      cn4[r] = cn;
    }

    if (t == NSTEP - 1) {
      if (lr < 4) {
        #pragma unroll
        for (int r = 0; r < 4; ++r) {
          int R = w * 16 + lk * 4 + r;
          out[(size_t)R * 1024 + j * 4 + lr]          = hv4[r];
          out[65536 + (size_t)R * 1024 + j * 4 + lr]  = hv4[r];
          out[131072 + (size_t)R * 1024 + j * 4 + lr] = cn4[r];
        }
      }
    } else {
      // tagged h store: data IS the flag. No ack, no barrier, no syncthreads.
      const u32 tag = (u32)(t + 1);
      u64* Xn = X3 + (size_t)((t + 1) % 3) * 32768;
      #pragma unroll
      for (int r = 0; r < 4; ++r) {
        float ho = __shfl_xor(hv4[r], 1);          // partner column's h
        if (lr < 4 && (lr & 1) == 0) {
          int R = w * 16 + lk * 4 + r;
          u64 pk = (u64)((u32)f2bf(hv4[r]) | ((u32)f2bf(ho) << 16))
                 | ((u64)tag << 32);
          AS(Xn + (size_t)R * 512 + j * 2 + (lr >> 1), pk);
        }
      }
    }
  }
#undef LDG
#undef MMG
}

extern "C" void kernel_launch(void* const* d_in, const int* in_sizes, int n_in,
                              void* d_out, int out_size, void* d_ws, size_t ws_size,
                              hipStream_t stream) {
  const int*   sent = (const int*)d_in[0];
  const float* emb  = (const float*)d_in[1];
  const float* w_ih = (const float*)d_in[2];
  const float* w_hh = (const float*)d_in[3];
  const float* b_ih = (const float*)d_in[4];
  const float* b_hh = (const float*)d_in[5];
  float* out = (float*)d_out;

  char* ws = (char*)d_ws;
  u16* A1 = (u16*)ws;                            // 32 MiB
  u64* X3 = (u64*)(ws + 33554432);               // 3 x 256 KiB tagged-h exchange

  prep_kernel<<<256, 256, 0, stream>>>(X3);
  gather_kernel<<<8192, 256, 0, stream>>>(sent, emb, A1);

  void* args[] = { (void*)&A1, (void*)&w_ih, (void*)&w_hh,
                   (void*)&b_ih, (void*)&b_hh, (void*)&X3, (void*)&out };
  hipError_t err = hipLaunchCooperativeKernel((void*)lstm_kernel, dim3(256), dim3(256),
                                              args, 0, stream);
  if (err != hipSuccess) {
    // dataflow kernel has no grid barrier; plain launch is fine when all 256
    // WGs are co-resident (1 WG/CU on a 256-CU part)
    lstm_kernel<<<dim3(256), dim3(256), 0, stream>>>(A1, w_ih, w_hh, b_ih, b_hh,
                                                     X3, out);
  }
}

// Round 12
// 5141.951 us; speedup vs baseline: 2.9355x; 2.9355x over previous
//
#include <hip/hip_runtime.h>

typedef __bf16 bf16x8 __attribute__((ext_vector_type(8)));
typedef float f32x4 __attribute__((ext_vector_type(4)));
typedef unsigned short u16;
typedef unsigned u32;
typedef unsigned long long u64;

#define NSTEP 512

#define AL(p)   __hip_atomic_load((p), __ATOMIC_RELAXED, __HIP_MEMORY_SCOPE_AGENT)
#define AS(p,v) __hip_atomic_store((p), (v), __ATOMIC_RELAXED, __HIP_MEMORY_SCOPE_AGENT)

__device__ __forceinline__ u16 f2bf(float f) {
  union { float f; unsigned u; } x; x.f = f;
  return (u16)((x.u + 0x7fffu + ((x.u >> 16) & 1u)) >> 16);
}

// zero h buffer 0 (UC, straight to L3) + barrier flags
__global__ void prep_kernel(u64* __restrict__ H0, int* __restrict__ bar) {
  int i = blockIdx.x * blockDim.x + threadIdx.x;
  if (i < 16384) AS(H0 + i, 0ULL);
  if (i < 16416) AS(&bar[i], 0);
}

// A1[t*64+b][512] bf16 embedding gather
__global__ void gather_kernel(const int* __restrict__ sent, const float* __restrict__ emb,
                              u16* __restrict__ A1) {
  int row = blockIdx.x * 4 + (threadIdx.x >> 6);   // t*64+b
  int lane = threadIdx.x & 63;
  int t = row >> 6, b = row & 63;
  int idx = sent[b * 512 + t];
  const float* src = emb + (size_t)idx * 512 + lane * 8;
  u16* dst = A1 + (size_t)row * 512 + lane * 8;
  #pragma unroll
  for (int k = 0; k < 8; ++k) dst[k] = f2bf(src[k]);
}

// 256 WGs x 256 thr. WG j owns h cols [j*4,j*4+4), 4 gates packed (rb = g*4+nn = lr).
// Weights in padded LDS. Barrier: r8's direct all-to-all epoch-flag poll.
// FRESH=1: h in 512 per-step buffers, written sc1 (bypass caches -> L3), read via
//   NORMAL cached loads — address never reused, so no stale-copy hazard; 32 WGs/XCD
//   share one set of L3 fills via their common L2.
// FRESH=0: exact r8 behavior (t%3 buffers + UC loads) as ws-size fallback.
template<int FRESH>
__global__ void __launch_bounds__(256, 2)
lstm_kernel(const u16* __restrict__ A1,
            const float* __restrict__ wih, const float* __restrict__ whh,
            const float* __restrict__ bih, const float* __restrict__ bhh,
            u16* __restrict__ H, float* __restrict__ out, int* __restrict__ bar) {
  __shared__ u16 wlds[48 * 16 * 36];        // 55296 B, stride-36 pad
  __shared__ alignas(8) u16 hx[4][16][4];   // per-wave h-store packing bounce

  const int j   = blockIdx.x;
  const int tid = threadIdx.x;
  const int w   = tid >> 6;            // wave = batch tile 0..3
  const int l   = tid & 63;
  const int lr  = l & 15, lk = l >> 4;
  const int g   = lr >> 2, nn = lr & 3;
  const int wrow = g * 1024 + j * 4 + nn;

  // ---- stage ALL weights fp32->bf16 into padded LDS (once) ----
  for (int task = tid; task < 3072; task += 256) {
    int kk = task >> 6;                 // K chunk of 32 (0..47)
    int rem = task & 63;
    int rb = rem >> 2, q = rem & 3;
    int row = (rb >> 2) * 1024 + j * 4 + (rb & 3);
    const float* src = (kk < 16) ? (wih + (size_t)row * 512 + kk * 32 + q * 8)
                                 : (whh + (size_t)row * 1024 + (kk - 16) * 32 + q * 8);
    u16* dst = wlds + (kk * 16 + rb) * 36 + q * 8;
    #pragma unroll
    for (int e = 0; e < 8; ++e) dst[e] = f2bf(src[e]);
  }
  __syncthreads();

  const float bias = bih[wrow] + bhh[wrow];
  const float sca = (g == 2) ? 2.f : 1.f;   // tanh-as-sigmoid scaling
  const float bd  = (g == 2) ? -1.f : 0.f;
  const int arow = w * 16 + lr;             // batch row for A fragments
  const u16* bx = wlds + lr * 36 + lk * 8;  // + kk*576 per K chunk

  float cst[4] = {0.f, 0.f, 0.f, 0.f};

  // prefetch A1 fragments for t=0
  bf16x8 ax[16];
  {
    const u16* apre = A1 + (size_t)arow * 512 + lk * 8;
    #pragma unroll
    for (int kk = 0; kk < 16; ++kk) ax[kk] = *(const bf16x8*)(apre + kk * 32);
  }

  union AF { bf16x8 v; u64 q[2]; };

#define LD8(BUF, CH)                                                        \
  { if constexpr (FRESH) {                                                  \
      _Pragma("unroll")                                                     \
      for (int r = 0; r < 8; ++r)                                           \
        BUF[r].v = *(const bf16x8*)(hp + (CH) * 256 + r * 32);              \
    } else {                                                                \
      _Pragma("unroll")                                                     \
      for (int r = 0; r < 8; ++r) {                                         \
        const u64* p = (const u64*)(hp + (CH) * 256 + r * 32);              \
        BUF[r].q[0] = AL(p); BUF[r].q[1] = AL(p + 1);                       \
      }                                                                     \
    } }
#define MM8(BUF, W0)                                                        \
  { _Pragma("unroll")                                                       \
    for (int r = 0; r < 8; ++r) {                                           \
      bf16x8 b = *(const bf16x8*)(bx + ((W0) + r) * 576);                   \
      acc = __builtin_amdgcn_mfma_f32_16x16x32_bf16(BUF[r].v, b, acc, 0, 0, 0); \
    } }

  #pragma unroll 1
  for (int t = 0; t < NSTEP; ++t) {
    AF ha[8], hb[8];
    const size_t hoff = FRESH ? (size_t)t * 65536 : (size_t)(t % 3) * 65536;
    const u16* hp = H + hoff + (size_t)arow * 1024 + lk * 8;
    LD8(ha, 0);                          // 32 h-loads in flight through x-proj
    LD8(hb, 1);
    // x-projection from prefetched ax (overlaps h-load latency)
    f32x4 acc = { bias, bias, bias, bias };
    #pragma unroll
    for (int kk = 0; kk < 16; ++kk) {
      bf16x8 b = *(const bf16x8*)(bx + kk * 576);
      acc = __builtin_amdgcn_mfma_f32_16x16x32_bf16(ax[kk], b, acc, 0, 0, 0);
    }
    // h-projection: double-buffered 8-fragment chunks
    MM8(ha, 16);
    LD8(ha, 2); MM8(hb, 24);
    LD8(hb, 3); MM8(ha, 32);
    MM8(hb, 40);

    // activations + state update; lanes lr<4 own (rows lk*4+r, col lr)
    float hv4[4], cn4[4];
    #pragma unroll
    for (int r = 0; r < 4; ++r) {
      float xv = acc[r];
      float act = sca / (1.f + __expf(-sca * xv)) + bd;  // sigmoid / tanh
      float gg = __shfl_xor(act, 8);
      float ff = __shfl_xor(act, 4);
      float oo = __shfl_xor(act, 12);
      float cn = ff * cst[r] + act * gg;   // act = i at lanes lr<4
      cst[r] = cn;
      float tc = 2.f / (1.f + __expf(-2.f * cn)) - 1.f;
      hv4[r] = oo * tc;
      cn4[r] = cn;
    }

    if (t == NSTEP - 1) {
      if (lr < 4) {
        #pragma unroll
        for (int r = 0; r < 4; ++r) {
          int R = w * 16 + lk * 4 + r;
          out[(size_t)R * 1024 + j * 4 + lr]          = hv4[r];
          out[65536 + (size_t)R * 1024 + j * 4 + lr]  = hv4[r];
          out[131072 + (size_t)R * 1024 + j * 4 + lr] = cn4[r];
        }
      }
    } else {
      // pack h tile 64x4 -> one 8B sc1 store per row (straight to L3)
      if (lr < 4) {
        #pragma unroll
        for (int r = 0; r < 4; ++r) hx[w][lk * 4 + r][lr] = f2bf(hv4[r]);
      }
      __syncthreads();
      const size_t noff = FRESH ? (size_t)(t + 1) * 65536 : (size_t)((t + 1) % 3) * 65536;
      if (l < 16) {
        u64 pk = *(const u64*)(&hx[w][l][0]);
        u16* hw = H + noff + (size_t)(w * 16 + l) * 1024 + j * 4;
        AS((u64*)hw, pk);
      }
      // h stores reach L3 before the arrival flag
      asm volatile("s_waitcnt vmcnt(0)" ::: "memory");
      __syncthreads();
      const int t1 = t + 1;
      if (tid == 0) AS(&bar[j * 32], t1);          // publish epoch (monotonic)
      // prefetch A1 for t+1; latency hides under the flag-wait window
      {
        const u16* apre = A1 + ((size_t)t1 * 64 + arow) * 512 + lk * 8;
        #pragma unroll
        for (int kk = 0; kk < 16; ++kk) ax[kk] = *(const bf16x8*)(apre + kk * 32);
      }
      // direct all-to-all wait: thread tid polls producer tid's epoch flag
      while (AL(&bar[tid * 32]) < t1) __builtin_amdgcn_s_sleep(1);
      __syncthreads();
    }
  }
#undef LD8
#undef MM8
}

extern "C" void kernel_launch(void* const* d_in, const int* in_sizes, int n_in,
                              void* d_out, int out_size, void* d_ws, size_t ws_size,
                              hipStream_t stream) {
  const int*   sent = (const int*)d_in[0];
  const float* emb  = (const float*)d_in[1];
  const float* w_ih = (const float*)d_in[2];
  const float* w_hh = (const float*)d_in[3];
  const float* b_ih = (const float*)d_in[4];
  const float* b_hh = (const float*)d_in[5];
  float* out = (float*)d_out;

  // tier A (FRESH): A1 32Mi | H 512x128Ki = 64Mi | bar  -> needs ~96.1 MiB
  // tier B:         A1 32Mi | H 3x128Ki           | bar  -> ~34 MiB (r8-proven)
  const int fresh = (ws_size >= (size_t)33554432 + 67108864 + 65664) ? 1 : 0;

  char* ws = (char*)d_ws;
  u16* A1 = (u16*)ws;                            // 32 MiB
  u16* H  = (u16*)(ws + 33554432);
  int* bar = fresh ? (int*)(ws + 33554432 + 67108864)
                   : (int*)(ws + 33554432 + 393216);

  prep_kernel<<<256, 256, 0, stream>>>((u64*)H, bar);
  gather_kernel<<<8192, 256, 0, stream>>>(sent, emb, A1);

  void* args[] = { (void*)&A1, (void*)&w_ih, (void*)&w_hh,
                   (void*)&b_ih, (void*)&b_hh, (void*)&H, (void*)&out, (void*)&bar };
  void* fn = fresh ? (void*)lstm_kernel<1> : (void*)lstm_kernel<0>;
  hipError_t err = hipLaunchCooperativeKernel(fn, dim3(256), dim3(256), args, 0, stream);
  if (err != hipSuccess) {
    // custom barrier (no cg grid.sync): plain launch is fine when all 256 WGs
    // are co-resident, which the 2-blocks/CU resource envelope guarantees
    if (fresh)
      lstm_kernel<1><<<dim3(256), dim3(256), 0, stream>>>(A1, w_ih, w_hh, b_ih, b_hh, H, out, bar);
    else
      lstm_kernel<0><<<dim3(256), dim3(256), 0, stream>>>(A1, w_ih, w_hh, b_ih, b_hh, H, out, bar);
  }
}